// Round 7
// baseline (847.094 us; speedup 1.0000x reference)
//
#include <hip/hip_runtime.h>
#include <math.h>

#define N_VAR 8192
#define N_CHK 4096
#define DV 3
#define N_EDGE (N_VAR * DV)
#define BATCH 128
#define T_ITERS 30
#define ELLW 24

#define LOG2E 1.44269504088896340736f
#define LN2   0.69314718055994530942f

// tanh(x/2), sign preserved, |t| floored at 1e-7 (matches reference clamp);
// x pre-clipped to [-15,15]
__device__ __forceinline__ float tanh_half(float x) {
    float ex = __builtin_amdgcn_exp2f(x * LOG2E);              // e^x
    float t = 1.0f - 2.0f * __builtin_amdgcn_rcpf(ex + 1.0f);
    float s = (x < 0.0f) ? -1.0f : 1.0f;
    return s * fmaxf(fabsf(t), 1e-7f);
}

// 2*atanh(clip(p)) — reference's clip(-1+eps, 1-eps) then 2 atanh
__device__ __forceinline__ float atanh2(float p) {
    const float lim = 1.0f - 1e-7f;
    p = fminf(fmaxf(p, -lim), lim);
    return (__builtin_amdgcn_logf(1.0f + p) -
            __builtin_amdgcn_logf(1.0f - p)) * LN2;
}

// ---------------- graph build (once per launch) ----------------------------

__global__ void k_ell_scatter(const int* __restrict__ edge_chk,
                              int* __restrict__ deg_arr, int* __restrict__ ell_e) {
    int e = blockIdx.x * blockDim.x + threadIdx.x;
    if (e < N_EDGE) {
        int c = edge_chk[e];
        int pos = atomicAdd(&deg_arr[c], 1);
        if (pos < ELLW) ell_e[c * ELLW + pos] = e;   // store EDGE id
    }
}

// exclusive prefix over 4096 degs -> ptr (compact slot offsets)
__global__ __launch_bounds__(1024) void k_scan(const int* __restrict__ counts,
                                               int* __restrict__ ptr) {
    __shared__ int bufA[1024];
    __shared__ int bufB[1024];
    int t = threadIdx.x;
    int c0 = counts[4 * t + 0];
    int c1 = counts[4 * t + 1];
    int c2 = counts[4 * t + 2];
    int c3 = counts[4 * t + 3];
    int s = c0 + c1 + c2 + c3;
    bufA[t] = s;
    __syncthreads();
    int* src = bufA;
    int* dst = bufB;
    for (int off = 1; off < 1024; off *= 2) {
        int v = src[t];
        if (t >= off) v += src[t - off];
        dst[t] = v;
        __syncthreads();
        int* tmp = src; src = dst; dst = tmp;
    }
    int incl = src[t];
    int excl = incl - s;
    ptr[4 * t + 0] = excl;
    ptr[4 * t + 1] = excl + c0;
    ptr[4 * t + 2] = excl + c0 + c1;
    ptr[4 * t + 3] = excl + c0 + c1 + c2;
    if (t == 1023) ptr[N_CHK] = incl;
}

// slot_e[e] = compact slot of edge e
__global__ void k_slotmap(const int* __restrict__ ell_e,
                          const int* __restrict__ deg_arr,
                          const int* __restrict__ ptr,
                          int* __restrict__ slot_e) {
    int gid = blockIdx.x * 256 + threadIdx.x;
    if (gid < N_CHK * ELLW) {
        int c = gid / ELLW;
        int j = gid - c * ELLW;
        int d = deg_arr[c]; if (d > ELLW) d = ELLW;
        if (j < d) slot_e[ell_e[gid]] = ptr[c] + j;
    }
}

// slot4[v] = slots of v's 3 edges (one 16B load in the hot kernel)
__global__ void k_slot4(const int* __restrict__ slot_e, int4* __restrict__ slot4) {
    int v = blockIdx.x * 256 + threadIdx.x;
    if (v < N_VAR) {
        int4 s;
        s.x = slot_e[3 * v + 0];
        s.y = slot_e[3 * v + 1];
        s.z = slot_e[3 * v + 2];
        s.w = 0;
        slot4[v] = s;
    }
}

// ---------------- persistent per-batch-element BP ---------------------------
// One block per batch element b. Entire message state lives in LDS:
//   s_c2v (fp16, check-compact slots) 48 KB, s_x (fp16) 48 KB.
// v2c state lives in f32 REGISTERS (var-side only access).
// All 30 iterations run inside the kernel; only __syncthreads() between
// var-phase and chk-phase. Posterior rows written coalesced to outT(T,B,V)
// (transposed later) or scattered to out directly if no scratch space.

__global__ __launch_bounds__(1024, 4) void k_bp(
        const float* __restrict__ chn,
        const float* __restrict__ gamma_logit,
        const int4* __restrict__ slot4,
        const int* __restrict__ deg_arr,
        const int* __restrict__ ptr,
        float* __restrict__ outT,      // (T, BATCH, N_VAR) scratch, or null
        float* __restrict__ outD) {    // (T, N_VAR, BATCH) final, used if !outT
    __shared__ _Float16 s_c2v[N_EDGE];    // 48 KB
    __shared__ _Float16 s_x[N_EDGE];      // 48 KB
    const int b = blockIdx.x;
    const int tid = threadIdx.x;

    for (int i = tid; i < N_EDGE; i += 1024) s_c2v[i] = (_Float16)0.0f;

    const float g = 1.0f / (1.0f + __builtin_amdgcn_exp2f(-gamma_logit[0] * LOG2E));
    const float om = 1.0f - g;

    float chn_r[8];
    float v2c_r[8][3];
#pragma unroll
    for (int k = 0; k < 8; ++k) {
        chn_r[k] = chn[(size_t)(tid + k * 1024) * BATCH + b];
        v2c_r[k][0] = 0.0f; v2c_r[k][1] = 0.0f; v2c_r[k][2] = 0.0f;
    }
    __syncthreads();

    const size_t SLICE = (size_t)N_VAR * BATCH;

    for (int t = 0; t < T_ITERS; ++t) {
        // ---- phase A: variables (8 per thread) ----
#pragma unroll
        for (int k = 0; k < 8; ++k) {
            int v = tid + k * 1024;
            int4 s4 = slot4[v];
            float c0 = (float)s_c2v[s4.x];
            float c1 = (float)s_c2v[s4.y];
            float c2 = (float)s_c2v[s4.z];
            float post = chn_r[k] + c0 + c1 + c2;
            if (t > 0) {
                if (outT) {
                    __builtin_nontemporal_store(post,
                        &outT[(size_t)(t - 1) * SLICE + (size_t)b * N_VAR + v]);
                } else {
                    __builtin_nontemporal_store(post,
                        &outD[(size_t)(t - 1) * SLICE + (size_t)v * BATCH + b]);
                }
            }
            float vn0 = g * (post - c0) + om * v2c_r[k][0];
            float vn1 = g * (post - c1) + om * v2c_r[k][1];
            float vn2 = g * (post - c2) + om * v2c_r[k][2];
            v2c_r[k][0] = vn0; v2c_r[k][1] = vn1; v2c_r[k][2] = vn2;
            s_x[s4.x] = (_Float16)fminf(fmaxf(vn0, -15.0f), 15.0f);
            s_x[s4.y] = (_Float16)fminf(fmaxf(vn1, -15.0f), 15.0f);
            s_x[s4.z] = (_Float16)fminf(fmaxf(vn2, -15.0f), 15.0f);
        }
        __syncthreads();

        // ---- phase B: checks (4 per thread) ----
#pragma unroll
        for (int m = 0; m < 4; ++m) {
            int c = tid + m * 1024;
            int deg = deg_arr[c];
            if (deg > ELLW) deg = ELLW;
            int base = ptr[c];
            if (deg > 0) {
                float tv[ELLW];
#pragma unroll
                for (int j = 0; j < ELLW; ++j)
                    if (j < deg) tv[j] = tanh_half((float)s_x[base + j]);
                float ext[ELLW];
                float run = 1.0f;
#pragma unroll
                for (int j = ELLW - 1; j >= 0; --j)
                    if (j < deg) { ext[j] = run; run *= tv[j]; }
                float pfx = 1.0f;
#pragma unroll
                for (int j = 0; j < ELLW; ++j)
                    if (j < deg) {
                        float p = pfx * ext[j];
                        pfx *= tv[j];
                        s_c2v[base + j] = (_Float16)atanh2(p);
                    }
            }
        }
        __syncthreads();
    }

    // ---- final posterior row (after last check update) ----
#pragma unroll
    for (int k = 0; k < 8; ++k) {
        int v = tid + k * 1024;
        int4 s4 = slot4[v];
        float post = chn_r[k] + (float)s_c2v[s4.x] + (float)s_c2v[s4.y] +
                     (float)s_c2v[s4.z];
        if (outT) {
            __builtin_nontemporal_store(post,
                &outT[(size_t)(T_ITERS - 1) * SLICE + (size_t)b * N_VAR + v]);
        } else {
            __builtin_nontemporal_store(post,
                &outD[(size_t)(T_ITERS - 1) * SLICE + (size_t)v * BATCH + b]);
        }
    }
}

// ---------------- transpose (T,B,V) -> (T,V,B) ------------------------------
// tile[b_local][v_local] = src[b][v]; write dst[v][b] = tile[lx][ly+i]
// (consecutive lx -> consecutive b in dst: coalesced; [32][33] kills bank
// conflicts on the transposed LDS read).

__global__ __launch_bounds__(256) void k_transpose(const float* __restrict__ src,
                                                   float* __restrict__ dst) {
    __shared__ float tile[32][33];
    int t = blockIdx.z;
    int v0 = blockIdx.x * 32;
    int b0 = blockIdx.y * 32;
    int lx = threadIdx.x;            // 32 wide
    int ly = threadIdx.y;            // 8
    const float* s = src + (size_t)t * N_VAR * BATCH;
    float* d = dst + (size_t)t * N_VAR * BATCH;
#pragma unroll
    for (int i = 0; i < 32; i += 8)
        tile[ly + i][lx] = s[(size_t)(b0 + ly + i) * N_VAR + v0 + lx];
    __syncthreads();
#pragma unroll
    for (int i = 0; i < 32; i += 8)
        __builtin_nontemporal_store(tile[lx][ly + i],
            &d[(size_t)(v0 + ly + i) * BATCH + b0 + lx]);
}

// ---------------- Launch ---------------------------------------------------

extern "C" void kernel_launch(void* const* d_in, const int* in_sizes, int n_in,
                              void* d_out, int out_size, void* d_ws, size_t ws_size,
                              hipStream_t stream) {
    const float* chn         = (const float*)d_in[0];
    const float* gamma_logit = (const float*)d_in[1];
    // d_in[2] = edge_var (deterministic: e/3) — not needed
    const int* edge_chk      = (const int*)d_in[3];
    float* out = (float*)d_out;

    // workspace layout: tables first, then (optional) transposed out scratch
    int4* slot4  = (int4*)d_ws;                            // N_VAR
    int* slot_e  = (int*)(slot4 + N_VAR);                  // N_EDGE
    int* ell_e   = slot_e + N_EDGE;                        // N_CHK*ELLW
    int* deg_arr = ell_e + (size_t)N_CHK * ELLW;           // N_CHK
    int* ptr     = deg_arr + N_CHK;                        // N_CHK+1
    size_t table_bytes = (char*)(ptr + N_CHK + 1) - (char*)d_ws;
    size_t outT_off = (table_bytes + 255) & ~(size_t)255;
    size_t outT_bytes = (size_t)T_ITERS * N_VAR * BATCH * sizeof(float);
    float* outT = (ws_size >= outT_off + outT_bytes)
                      ? (float*)((char*)d_ws + outT_off) : (float*)0;

    (void)hipMemsetAsync(slot_e, 0, (size_t)N_EDGE * sizeof(int), stream);
    (void)hipMemsetAsync(deg_arr, 0, N_CHK * sizeof(int), stream);

    k_ell_scatter<<<(N_EDGE + 255) / 256, 256, 0, stream>>>(edge_chk, deg_arr,
                                                            ell_e);
    k_scan<<<1, 1024, 0, stream>>>(deg_arr, ptr);
    k_slotmap<<<(N_CHK * ELLW + 255) / 256, 256, 0, stream>>>(ell_e, deg_arr,
                                                              ptr, slot_e);
    k_slot4<<<N_VAR / 256, 256, 0, stream>>>(slot_e, slot4);

    k_bp<<<BATCH, 1024, 0, stream>>>(chn, gamma_logit, slot4, deg_arr, ptr,
                                     outT, out);

    if (outT) {
        dim3 tg(N_VAR / 32, BATCH / 32, T_ITERS);
        dim3 tb(32, 8, 1);
        k_transpose<<<tg, tb, 0, stream>>>(outT, out);
    }
}